// Round 1
// 547.440 us; speedup vs baseline: 1.0182x; 1.0182x over previous
//
#include <hip/hip_runtime.h>

// Problem constants (match reference setup_inputs)
constexpr int   B_   = 8;
constexpr int   RES  = 160;
constexpr long long GCELLS = (long long)B_ * RES * RES * RES;   // 32,768,000
constexpr float EMA  = 0.95f;
constexpr float THRE = 0.01f;

// ext_vector types so __builtin_nontemporal_{load,store} accept them
typedef float        f32x4 __attribute__((ext_vector_type(4)));
typedef int          i32x4 __attribute__((ext_vector_type(4)));
typedef unsigned int u32x4 __attribute__((ext_vector_type(4)));

// Pass 0: zero the scratch with REGULAR (cache-allocating) stores.
// We want the zeroed lines resident in LLC so the scatter's atomics hit cache.
__global__ void __launch_bounds__(256)
occ_zero_kernel(u32x4* __restrict__ scratch, long long nquads) {
    long long i = (long long)blockIdx.x * blockDim.x + threadIdx.x;
    if (i >= nquads) return;
    u32x4 z = {0u, 0u, 0u, 0u};
    scratch[i] = z;
}

// Pass 1: per-point scatter, 4 points per thread.
// scratch[lin] = atomicMax over (float_bits(val)+1). val >= 0 so uint compare of
// float bits is monotone; +1 makes 0 a clean "untouched" sentinel (reversible s-1).
__global__ void __launch_bounds__(256)
occ_scatter_kernel(const f32x4* __restrict__ pts4,
                   const i32x4* __restrict__ bidx4,
                   const f32x4* __restrict__ val4,
                   const float* __restrict__ pts,
                   const int*   __restrict__ bidx,
                   const float* __restrict__ val,
                   unsigned int* __restrict__ scratch,
                   int nq, int rem) {
    int i = blockIdx.x * blockDim.x + threadIdx.x;
    if (i < nq) {
        // 4 points = 3 consecutive float4 loads (48 B), fully vectorized
        f32x4 p0 = pts4[3 * i + 0];
        f32x4 p1 = pts4[3 * i + 1];
        f32x4 p2 = pts4[3 * i + 2];
        i32x4 b  = bidx4[i];
        f32x4 v  = val4[i];

        float px[4] = {p0.x, p0.w, p1.z, p2.y};
        float py[4] = {p0.y, p1.x, p1.w, p2.z};
        float pz[4] = {p0.z, p1.y, p2.x, p2.w};
        int   bb[4] = {b.x, b.y, b.z, b.w};
        float vv[4] = {v.x, v.y, v.z, v.w};

#pragma unroll
        for (int k = 0; k < 4; ++k) {
            // Match jnp: ((p / 2 + 0.5) * res).astype(int32), clamped to [0, res-1].
            int gx = (int)((px[k] / 2.0f + 0.5f) * (float)RES);
            int gy = (int)((py[k] / 2.0f + 0.5f) * (float)RES);
            int gz = (int)((pz[k] / 2.0f + 0.5f) * (float)RES);
            gx = min(max(gx, 0), RES - 1);
            gy = min(max(gy, 0), RES - 1);
            gz = min(max(gz, 0), RES - 1);
            int lin = ((bb[k] * RES + gx) * RES + gy) * RES + gz;   // < 2^31
            atomicMax(&scratch[lin], __float_as_uint(vv[k]) + 1u);
        }
    } else if (i == nq && rem > 0) {
        // scalar tail (N % 4 points), normally rem == 0
        for (int k = 0; k < rem; ++k) {
            int j = nq * 4 + k;
            float x = pts[3 * j + 0];
            float y = pts[3 * j + 1];
            float z = pts[3 * j + 2];
            int gx = (int)((x / 2.0f + 0.5f) * (float)RES);
            int gy = (int)((y / 2.0f + 0.5f) * (float)RES);
            int gz = (int)((z / 2.0f + 0.5f) * (float)RES);
            gx = min(max(gx, 0), RES - 1);
            gy = min(max(gy, 0), RES - 1);
            gz = min(max(gz, 0), RES - 1);
            int lin = ((bidx[j] * RES + gx) * RES + gy) * RES + gz;
            atomicMax(&scratch[lin], __float_as_uint(val[j]) + 1u);
        }
    }
}

// Pass 2: per-cell finalize.
// grid is streamed with NON-TEMPORAL loads (don't evict the LLC-hot scratch);
// outputs use NON-TEMPORAL stores (never re-read -> don't thrash the 256 MB LLC,
// so inputs/scratch stay resident across graph-replay iterations).
__global__ void __launch_bounds__(256)
occ_finalize_kernel(const f32x4* __restrict__ grid,
                    f32x4* __restrict__ out_val,
                    f32x4* out_occ /* aliases scratch (u32-encoded) */,
                    long long nquads) {
    long long i = (long long)blockIdx.x * blockDim.x + threadIdx.x;
    if (i >= nquads) return;

    f32x4 g = __builtin_nontemporal_load(&grid[i]);
    u32x4 s = *reinterpret_cast<const u32x4*>(&out_occ[i]);   // regular load: LLC-hot

    f32x4 r;
    r.x = s.x ? fmaxf(g.x * EMA, __uint_as_float(s.x - 1u)) : g.x;
    r.y = s.y ? fmaxf(g.y * EMA, __uint_as_float(s.y - 1u)) : g.y;
    r.z = s.z ? fmaxf(g.z * EMA, __uint_as_float(s.z - 1u)) : g.z;
    r.w = s.w ? fmaxf(g.w * EMA, __uint_as_float(s.w - 1u)) : g.w;

    f32x4 o;
    o.x = (r.x > THRE) ? 1.0f : 0.0f;
    o.y = (r.y > THRE) ? 1.0f : 0.0f;
    o.z = (r.z > THRE) ? 1.0f : 0.0f;
    o.w = (r.w > THRE) ? 1.0f : 0.0f;

    __builtin_nontemporal_store(r, &out_val[i]);
    __builtin_nontemporal_store(o, &out_occ[i]);
}

extern "C" void kernel_launch(void* const* d_in, const int* in_sizes, int n_in,
                              void* d_out, int out_size, void* d_ws, size_t ws_size,
                              hipStream_t stream) {
    const float* grid = (const float*)d_in[0];   // (B,R,R,R) fp32
    const float* pts  = (const float*)d_in[1];   // (N,3) fp32
    const int*   bidx = (const int*)d_in[2];     // (N,) int32
    const float* val  = (const float*)d_in[3];   // (N,) fp32

    float* out_val = (float*)d_out;              // first G floats: new grid
    float* out_occ = out_val + GCELLS;           // second G floats: occ mask / scratch

    int n   = in_sizes[1] / 3;                   // N points
    int nq  = n / 4;
    int rem = n % 4;

    long long quads = GCELLS / 4;                // 8,192,000 (divisible by 256)
    int cell_blocks = (int)((quads + 255) / 256);

    // Pass 0: zero scratch (cache-allocating stores keep zeros LLC-resident)
    occ_zero_kernel<<<cell_blocks, 256, 0, stream>>>((u32x4*)out_occ, quads);

    // Pass 1: scatter (4 pts/thread + scalar tail thread)
    int sb = (nq + 1 + 255) / 256;
    occ_scatter_kernel<<<sb, 256, 0, stream>>>(
        (const f32x4*)pts, (const i32x4*)bidx, (const f32x4*)val,
        pts, bidx, val, (unsigned int*)out_occ, nq, rem);

    // Pass 2: finalize (NT grid load, NT output stores)
    occ_finalize_kernel<<<cell_blocks, 256, 0, stream>>>(
        (const f32x4*)grid, (f32x4*)out_val, (f32x4*)out_occ, quads);
}